// Round 13
// baseline (233.446 us; speedup 1.0000x reference)
//
#include <hip/hip_runtime.h>
#include <stdint.h>

// GQA fused forward: B=2, S=1024, HIDDEN=2048, H=32, G=8, D=64, causal.
// I/O float32; internal bf16 MFMA. Mask input ignored (causal from indices).
//
// Pipeline (round 13: BARRIER-FREE attention -- K/V direct from global):
//   0) cvt:       f32 -> bf16 copies of x, Wq, Wk, Wv, Wo (exact-fit 1D grid)
//   1) qkv_gemm:  128x64 tiles, 768 blocks (3/CU), dbuf staging, fused
//                 bias+scatter (direct stores). XCD-rect swizzle 8m x 12ty.
//   2) attn:      S^T-form flash attention, paired q-tiles. K/V MFMA
//                 fragments loaded DIRECTLY from global into VGPRs (the LDS
//                 stage+swizzle-read pair was an identity). sPt is wave-
//                 private -> ZERO barriers in the kc loop (was 2/step:
//                 r12 profile showed 1700 cy/step for ~500 cy of work --
//                 the vmcnt(0)+s_barrier convoy). V issued at step-top,
//                 consumed ~1000cy later; next K prefetched into regs (T14).
//                 Diagonal-only masking, exact skip-rescale, v_perm packing.
//   3) out_gemm:  dbuf core, 512 blocks (2/CU), fused bias -> f32 out
//                 (direct stores). XCD-rect swizzle 8m x 8ty.
//
// NOTE (round-1): never fuse cross-block reductions via atomics+fences
// (device __threadfence -> buffer_wbl2/inv, 38us -> 150us).
// NOTE (round-4): staging-queue contention at 4 blocks/CU regressed attn
// (35->50us) -- moot now (no global_load_lds in attn), but keep 2 blocks/CU
// paired structure: uniform load, XCD-balanced.
// NOTE (round-6): GEMMs are staging/issue-latency-bound, not HBM-BW-bound.
// NOTE (round-7): weights must reach GEMMs as bf16 via global_load_lds.
// NOTE (round-8): GEMM dbuf neutral (TLP already hides staging latency).
// NOTE (round-9/10): attn VALU diet + KV-sharing neutral -> the cost was
// never VALU or staging bytes; r12 profile isolated it: barrier convoy.
// NOTE (round-11): LDS-bounce epilogues regressed (write-side bank
// conflicts + 2 barriers); store issue is not on the critical path.

typedef __bf16 bf16_8 __attribute__((ext_vector_type(8)));
typedef float f32x4 __attribute__((ext_vector_type(4)));

__device__ __forceinline__ unsigned short f2bf(float f) {
  union { float f; unsigned int i; } c; c.f = f;
  unsigned int u = c.i;
  return (unsigned short)((u + 0x7fffu + ((u >> 16) & 1u)) >> 16);
}

__device__ __forceinline__ void gl2lds16(const void* g, void* l) {
  __builtin_amdgcn_global_load_lds(
      (const __attribute__((address_space(1))) void*)g,
      (__attribute__((address_space(3))) void*)l, 16, 0, 0);
}

// Stage ROWS x 64 bf16 tile (leading dim ldg) into LDS; per-row XOR swizzle of
// 8-elem groups: LDS[r][lg] = G[r][lg ^ (r&7)]. 256 threads.
template <int ROWS>
__device__ __forceinline__ void stage_tile(const unsigned short* g, int ldg,
                                           unsigned short* lds, int tid) {
#pragma unroll
  for (int i = 0; i < ROWS * 8 / 256; ++i) {
    int c = tid + i * 256;
    int r = c >> 3;
    int grp = (c & 7) ^ (r & 7);
    gl2lds16(g + (size_t)r * ldg + grp * 8, lds + c * 8);
  }
}

// Core 128x64 GEMM tile: Y = X[128,K] @ W[64,K]^T (leading dim ld).
// 4 waves, each owns a 32x64 output stripe: acc[2][4] of 16x16 frags.
// Double-buffered: one barrier per K-step; stage(k+1) issued before MFMA(k).
__device__ __forceinline__ void gemm_core_n64(const unsigned short* Xt,
                                              const unsigned short* Wt,
                                              int kiter, int ld, int tid,
                                              unsigned short* sA,
                                              unsigned short* sB,
                                              f32x4 acc[2][4]) {
  const int wave = tid >> 6, lane = tid & 63;
  const int wm = wave << 5;
  const int lrow = lane & 15, quad = lane >> 4;
  stage_tile<128>(Xt, ld, sA, tid);
  stage_tile<64>(Wt, ld, sB, tid);
  int cur = 0;
  for (int k0 = 0; k0 < kiter; k0 += 64) {
    __syncthreads();  // staging(buf[cur]) drained; buf[cur^1] reads done
    if (k0 + 64 < kiter) {
      stage_tile<128>(Xt + k0 + 64, ld, sA + ((cur ^ 1) << 13), tid);
      stage_tile<64>(Wt + k0 + 64, ld, sB + ((cur ^ 1) << 12), tid);
    }
    const unsigned short* A = sA + (cur << 13);
    const unsigned short* Bt = sB + (cur << 12);
#pragma unroll
    for (int ks = 0; ks < 2; ++ks) {
      bf16_8 af[2], bw[4];
#pragma unroll
      for (int i = 0; i < 2; ++i) {
        int ra = wm + i * 16 + lrow;
        af[i] = *(const bf16_8*)(A + ra * 64 + (((ks << 2) + quad) ^ (ra & 7)) * 8);
      }
#pragma unroll
      for (int j = 0; j < 4; ++j) {
        int rb = j * 16 + lrow;
        bw[j] = *(const bf16_8*)(Bt + rb * 64 + (((ks << 2) + quad) ^ (rb & 7)) * 8);
      }
#pragma unroll
      for (int i = 0; i < 2; ++i)
#pragma unroll
        for (int j = 0; j < 4; ++j)
          acc[i][j] = __builtin_amdgcn_mfma_f32_16x16x32_bf16(af[i], bw[j],
                                                              acc[i][j], 0, 0, 0);
    }
    cur ^= 1;
  }
}

// ---------------- kernel 0: f32 -> bf16 conversion (exact-fit 1D grid) ------
// 14336 blocks: x 4096 | Wq 4096 | Wk 1024 | Wv 1024 | Wo 4096.
__global__ void __launch_bounds__(256)
cvt_kernel(const float* __restrict__ s0, const float* __restrict__ s1,
           const float* __restrict__ s2, const float* __restrict__ s3,
           const float* __restrict__ s4,
           unsigned short* __restrict__ d0, unsigned short* __restrict__ d1,
           unsigned short* __restrict__ d2, unsigned short* __restrict__ d3,
           unsigned short* __restrict__ d4) {
  const int bid = blockIdx.x;
  const float* src; unsigned short* dst; int off;
  if (bid < 4096)       { src = s0; dst = d0; off = bid; }
  else if (bid < 8192)  { src = s1; dst = d1; off = bid - 4096; }
  else if (bid < 9216)  { src = s2; dst = d2; off = bid - 8192; }
  else if (bid < 10240) { src = s3; dst = d3; off = bid - 9216; }
  else                  { src = s4; dst = d4; off = bid - 10240; }
  int idx = (off * 256 + threadIdx.x) * 4;
  float4 v = *(const float4*)(src + idx);
  ushort4 o;
  o.x = f2bf(v.x); o.y = f2bf(v.y); o.z = f2bf(v.z); o.w = f2bf(v.w);
  *(ushort4*)(dst + idx) = o;
}

// ---------------- kernel 1: QKV projection, fused bias+scatter -------------
// 1D grid (768). XCD-rect swizzle: xcd=bid&7 owns an 8m x 12ty rectangle.
// ty 0..31 -> Q head ty; 32..39 -> K group; 40..47 -> V group (n = ty*64).
__global__ void __launch_bounds__(256)
qkv_gemm(const unsigned short* __restrict__ X,
         const unsigned short* __restrict__ Wq,
         const unsigned short* __restrict__ Wk,
         const unsigned short* __restrict__ Wv,
         const float* __restrict__ bq, const float* __restrict__ bk,
         const float* __restrict__ bv,
         unsigned short* __restrict__ qws, unsigned short* __restrict__ kws,
         unsigned short* __restrict__ vws) {
  __shared__ unsigned short sA[2 * 128 * 64], sB[2 * 64 * 64];
  const int tid = threadIdx.x;
  const int bid = blockIdx.x;
  const int xcd = bid & 7, idx = bid >> 3;        // 96 blocks per XCD
  const int mt  = ((xcd & 1) << 3) + idx / 12;    // [0,16)
  const int ty  = (xcd >> 1) * 12 + idx % 12;     // [0,48)
  const int tileM = mt * 128;
  const unsigned short* W;
  const float* bias;
  if (ty < 32)      { W = Wq + (size_t)ty * 64 * 2048;        bias = bq + ty * 64; }
  else if (ty < 40) { W = Wk + (size_t)(ty - 32) * 64 * 2048; bias = bk + (ty - 32) * 64; }
  else              { W = Wv + (size_t)(ty - 40) * 64 * 2048; bias = bv + (ty - 40) * 64; }

  f32x4 acc[2][4] = {};
  gemm_core_n64(X + (size_t)tileM * 2048, W, 2048, 2048, tid, sA, sB, acc);

  const int wave = tid >> 6, lane = tid & 63;
  const int wm = wave << 5;
  const int lrow = lane & 15, quad = lane >> 4;

#pragma unroll
  for (int j = 0; j < 4; ++j) {
    const int dloc = j * 16 + lrow;          // 0..63: dim within this 64-slice
    const float bj = bias[dloc];
#pragma unroll
    for (int i = 0; i < 2; ++i) {
      const int mbase = tileM + wm + i * 16 + quad * 4;
      const int b = mbase >> 10;
      const int s = mbase & 1023;            // s, s+1, s+2, s+3 for r=0..3
      if (ty < 32) {
        unsigned short* p = qws + ((((size_t)b * 32 + ty) << 10) + s) * 64 + dloc;
#pragma unroll
        for (int r = 0; r < 4; ++r) p[r * 64] = f2bf(acc[i][j][r] + bj);
      } else if (ty < 40) {
        unsigned short* p = kws + ((((size_t)b * 8 + (ty - 32)) << 10) + s) * 64 + dloc;
#pragma unroll
        for (int r = 0; r < 4; ++r) p[r * 64] = f2bf(acc[i][j][r] + bj);
      } else {
        // vws[b, g, d, s] (transposed): r=0..3 are consecutive s -> pack 8B
        unsigned short* p = vws + ((((size_t)b * 8 + (ty - 40)) * 64 + dloc) << 10) + s;
        uint2 pk;
        pk.x = f2bf(acc[i][j][0] + bj) | ((unsigned int)f2bf(acc[i][j][1] + bj) << 16);
        pk.y = f2bf(acc[i][j][2] + bj) | ((unsigned int)f2bf(acc[i][j][3] + bj) << 16);
        *(uint2*)p = pk;
      }
    }
  }
}

// ---------------- attn tile step (register K/V fragments) -------------------
// MASKED=true only for the diagonal tile (kc==qt). Skip-rescale when the
// running max doesn't grow (alpha==1.0 bit-exactly). v_perm_b32 packing.
// sPt is WAVE-PRIVATE (rows qloc = wave*16+lrow): no barriers needed.
template <bool MASKED>
__device__ __forceinline__ void attn_step(
    const bf16_8 (&kf)[2][4], const bf16_8 (&vf)[2][4],
    unsigned short* __restrict__ sPt,
    const bf16_8 (&qf)[2], int lrow, int quad, int qloc,
    int kvb, int q_g, float C, float& m_i, float& l_i, f32x4 (&o)[4]) {
  f32x4 sc[4] = {};
  __builtin_amdgcn_s_setprio(1);
#pragma unroll
  for (int kh = 0; kh < 2; ++kh)
#pragma unroll
    for (int mt = 0; mt < 4; ++mt)
      sc[mt] = __builtin_amdgcn_mfma_f32_16x16x32_bf16(kf[kh][mt], qf[kh],
                                                       sc[mt], 0, 0, 0);
  __builtin_amdgcn_s_setprio(0);

  float mx = -INFINITY;
#pragma unroll
  for (int mt = 0; mt < 4; ++mt)
#pragma unroll
    for (int r = 0; r < 4; ++r) {
      float v = sc[mt][r];
      if constexpr (MASKED) {
        if (kvb + mt * 16 + r > q_g) v = -INFINITY;
        sc[mt][r] = v;
      }
      mx = fmaxf(mx, v);
    }
  mx = fmaxf(mx, __shfl_xor(mx, 16));
  mx = fmaxf(mx, __shfl_xor(mx, 32));

  const bool grow = __any(mx > m_i);
  float alpha = 1.f;
  if (grow) {
    float mnew = fmaxf(m_i, mx);
    alpha = exp2f((m_i - mnew) * C);
    m_i = mnew;
  }
  float sum = 0.f;
#pragma unroll
  for (int mt = 0; mt < 4; ++mt)
#pragma unroll
    for (int r = 0; r < 4; ++r) {
      float p = exp2f((sc[mt][r] - m_i) * C);
      sc[mt][r] = p;
      sum += p;
    }
  sum += __shfl_xor(sum, 16);
  sum += __shfl_xor(sum, 32);
  if (grow) {
    l_i = l_i * alpha + sum;
#pragma unroll
    for (int mt = 0; mt < 4; ++mt)
#pragma unroll
      for (int r = 0; r < 4; ++r) o[mt][r] *= alpha;
  } else {
    l_i += sum;
  }

#pragma unroll
  for (int mt = 0; mt < 4; ++mt) {
    unsigned int a0 = __float_as_uint(sc[mt][0]), a1 = __float_as_uint(sc[mt][1]);
    unsigned int a2 = __float_as_uint(sc[mt][2]), a3 = __float_as_uint(sc[mt][3]);
    uint2 pk;
    pk.x = __builtin_amdgcn_perm(a1, a0, 0x07060302u);  // (a0>>16)|(a1&hi16)
    pk.y = __builtin_amdgcn_perm(a3, a2, 0x07060302u);
    int grp = (mt * 4 + quad) ^ lrow;
    *(uint2*)(sPt + qloc * 64 + grp * 4) = pk;
  }

  __builtin_amdgcn_s_setprio(1);
#pragma unroll
  for (int kh = 0; kh < 2; ++kh) {
    int gbase = kh * 8 + quad * 2;
    uint2 b0 = *(const uint2*)(sPt + qloc * 64 + ((gbase) ^ lrow) * 4);
    uint2 b1 = *(const uint2*)(sPt + qloc * 64 + ((gbase + 1) ^ lrow) * 4);
    union { uint4 u; bf16_8 v; } bb;
    bb.u = make_uint4(b0.x, b0.y, b1.x, b1.y);
#pragma unroll
    for (int mt = 0; mt < 4; ++mt)
      o[mt] = __builtin_amdgcn_mfma_f32_16x16x32_bf16(vf[kh][mt], bb.v,
                                                      o[mt], 0, 0, 0);
  }
  __builtin_amdgcn_s_setprio(0);
}

// ---------------- kernel 2: causal flash attention (S^T form) ----------------
// grid (8, 32, 2): (pair, head, batch). Block handles q-tiles {x, 15-x}:
// uniform 17 kc-iters per block, XCD-balanced. K/V fragments loaded DIRECTLY
// from global (16B contiguous each; the old LDS stage+swizzle-read pair was
// an identity). sPt wave-private -> the kc loop has NO barriers; waves run
// independently (latency overlap without lockstep). V issued at step-top and
// consumed ~1000cy later; next-step K prefetched into a 2nd register set.
// Only 2 barriers per q-tile remain (around the cross-wave O writeback).
__global__ void __launch_bounds__(256, 2)
attn_kernel(const unsigned short* __restrict__ Qw, const unsigned short* __restrict__ Kw,
            const unsigned short* __restrict__ Vt, unsigned short* __restrict__ Ow) {
  __shared__ unsigned short sPt[64 * 64];
  const int tid = threadIdx.x;
  const int pair = blockIdx.x, h = blockIdx.y, b = blockIdx.z;
  const int g = h >> 2;
  const unsigned short* Kb = Kw + (((size_t)b * 8 + g) << 16);  // [s][d] ld=64
  const unsigned short* Vb = Vt + (((size_t)b * 8 + g) << 16);  // [d][s] ld=1024
  const int wave = tid >> 6, lane = tid & 63;
  const int lrow = lane & 15, quad = lane >> 4;
  const int qloc = wave * 16 + lrow;
  const int colo = ((quad)) * 8;  // base d/s offset of this lane's 16B frag
  const float C = 0.18033688f;  // 0.125 * log2(e)

#pragma unroll 1
  for (int t = 0; t < 2; ++t) {
    const int qt = t ? (15 - pair) : pair;
    __syncthreads();  // protect sPt reuse across t iterations

    // Q fragments straight from global: Q[b,h, qt*64+qloc, (kh*4+quad)*8 ..+8]
    const unsigned short* Qrow =
        Qw + ((((size_t)b * 32 + h) << 10) + qt * 64 + qloc) * 64;
    bf16_8 qf[2];
#pragma unroll
    for (int kh = 0; kh < 2; ++kh)
      qf[kh] = *(const bf16_8*)(Qrow + kh * 32 + colo);

    // prologue: K fragments for kc=0
    bf16_8 kf[2][4], kn[2][4], vf[2][4];
#pragma unroll
    for (int kh = 0; kh < 2; ++kh)
#pragma unroll
      for (int mt = 0; mt < 4; ++mt)
        kf[kh][mt] = *(const bf16_8*)(Kb + (size_t)(mt * 16 + lrow) * 64 +
                                      kh * 32 + colo);

    float m_i = -INFINITY, l_i = 0.f;
    f32x4 o[4] = {};
    const int q_g = qt * 64 + qloc;

    // non-diagonal tiles: no causal masking possible, NO barriers
#pragma unroll 1
    for (int kc = 0; kc < qt; ++kc) {
      const unsigned short* Vc = Vb + kc * 64;
      const unsigned short* Kn = Kb + (size_t)(kc + 1) * 64 * 64;
      // V for this step: consumed at step end (~1000cy) -> self-hiding
#pragma unroll
      for (int kh = 0; kh < 2; ++kh)
#pragma unroll
        for (int mt = 0; mt < 4; ++mt)
          vf[kh][mt] = *(const bf16_8*)(Vc + (size_t)(mt * 16 + lrow) * 1024 +
                                        kh * 32 + colo);
      // K for next step: consumed next iteration -> fully hidden
#pragma unroll
      for (int kh = 0; kh < 2; ++kh)
#pragma unroll
        for (int mt = 0; mt < 4; ++mt)
          kn[kh][mt] = *(const bf16_8*)(Kn + (size_t)(mt * 16 + lrow) * 64 +
                                        kh * 32 + colo);
      attn_step<false>(kf, vf, sPt, qf, lrow, quad, qloc,
                       kc * 64 + quad * 4, q_g, C, m_i, l_i, o);
#pragma unroll
      for (int kh = 0; kh < 2; ++kh)
#pragma unroll
        for (int mt = 0; mt < 4; ++mt) kf[kh][mt] = kn[kh][mt];
    }
    // diagonal tile (kc == qt): the only tile the causal mask touches
    {
      const unsigned short* Vc = Vb + qt * 64;
#pragma unroll
      for (int kh = 0; kh < 2; ++kh)
#pragma unroll
        for (int mt = 0; mt < 4; ++mt)
          vf[kh][mt] = *(const bf16_8*)(Vc + (size_t)(mt * 16 + lrow) * 1024 +
                                        kh * 32 + colo);
      attn_step<true>(kf, vf, sPt, qf, lrow, quad, qloc,
                      qt * 64 + quad * 4, q_g, C, m_i, l_i, o);
    }

    float inv = 1.f / l_i;
#pragma unroll
    for (int mt = 0; mt < 4; ++mt) {
      uint2 pk;
      pk.x = f2bf(o[mt][0] * inv) | ((unsigned int)f2bf(o[mt][1] * inv) << 16);
      pk.y = f2bf(o[mt][2] * inv) | ((unsigned int)f2bf(o[mt][3] * inv) << 16);
      int grp = (mt * 4 + quad) ^ lrow;
      *(uint2*)(sPt + qloc * 64 + grp * 4) = pk;
    }
    __syncthreads();
    {
      int row = tid >> 2, seg = tid & 3;
      uint2 w0 = *(const uint2*)(sPt + row * 64 + ((seg * 4 + 0) ^ (row & 15)) * 4);
      uint2 w1 = *(const uint2*)(sPt + row * 64 + ((seg * 4 + 1) ^ (row & 15)) * 4);
      uint2 w2 = *(const uint2*)(sPt + row * 64 + ((seg * 4 + 2) ^ (row & 15)) * 4);
      uint2 w3 = *(const uint2*)(sPt + row * 64 + ((seg * 4 + 3) ^ (row & 15)) * 4);
      size_t base = ((((size_t)b << 10) + qt * 64 + row) << 11) + h * 64 + seg * 16;
      *(uint4*)(Ow + base) = make_uint4(w0.x, w0.y, w1.x, w1.y);
      *(uint4*)(Ow + base + 8) = make_uint4(w2.x, w2.y, w3.x, w3.y);
    }
  }
}

// ---------------- kernel 3: output projection, fused bias -> f32 out --------
// 1D grid (512). XCD-rect swizzle: xcd=bid&7 owns an 8m x 8ty rectangle.
// Direct epilogue stores (r11 lesson).
__global__ void __launch_bounds__(256)
out_gemm(const unsigned short* __restrict__ X, const unsigned short* __restrict__ Wo,
         const float* __restrict__ bo, float* __restrict__ out) {
  __shared__ unsigned short sA[2 * 128 * 64], sB[2 * 64 * 64];
  const int tid = threadIdx.x;
  const int bid = blockIdx.x;
  const int xcd = bid & 7, idx = bid >> 3;        // 64 blocks per XCD
  const int mt  = ((xcd & 1) << 3) + (idx >> 3);  // [0,16)
  const int ty  = ((xcd >> 1) << 3) + (idx & 7);  // [0,32)
  const int tileM = mt * 128, tileN = ty * 64;
  f32x4 acc[2][4] = {};
  gemm_core_n64(X + (size_t)tileM * 2048, Wo + (size_t)tileN * 2048, 2048, 2048,
                tid, sA, sB, acc);

  const int wave = tid >> 6, lane = tid & 63;
  const int wm = wave << 5;
  const int lrow = lane & 15, quad = lane >> 4;
#pragma unroll
  for (int j = 0; j < 4; ++j) {
    const int n = tileN + j * 16 + lrow;
    const float bj = bo[n];
#pragma unroll
    for (int i = 0; i < 2; ++i) {
      const int mbase = tileM + wm + i * 16 + quad * 4;
#pragma unroll
      for (int r = 0; r < 4; ++r)
        out[(size_t)(mbase + r) * 2048 + n] = acc[i][j][r] + bj;
    }
  }
}

extern "C" void kernel_launch(void* const* d_in, const int* in_sizes, int n_in,
                              void* d_out, int out_size, void* d_ws, size_t ws_size,
                              hipStream_t stream) {
  const float* x  = (const float*)d_in[0];
  const float* Wq = (const float*)d_in[2];
  const float* bq = (const float*)d_in[3];
  const float* Wk = (const float*)d_in[4];
  const float* bk = (const float*)d_in[5];
  const float* Wv = (const float*)d_in[6];
  const float* bv = (const float*)d_in[7];
  const float* Wo = (const float*)d_in[8];
  const float* bo = (const float*)d_in[9];

  unsigned short* xbf  = (unsigned short*)d_ws;                  // 4,194,304 el
  unsigned short* wqbf = xbf  + (size_t)4194304;
  unsigned short* wkbf = wqbf + (size_t)4194304;
  unsigned short* wvbf = wkbf + (size_t)1048576;
  unsigned short* wobf = wvbf + (size_t)1048576;
  unsigned short* qws  = wobf + (size_t)4194304;                 // [2,32,1024,64]
  unsigned short* kws  = qws  + (size_t)2 * 32 * 1024 * 64;      // [2,8,1024,64]
  unsigned short* vws  = kws  + (size_t)2 * 8 * 1024 * 64;       // [2,8,64,1024]
  unsigned short* aws  = vws  + (size_t)2 * 8 * 1024 * 64;       // [2,1024,2048]
  float* out = (float*)d_out;

  hipLaunchKernelGGL(cvt_kernel, dim3(14336), dim3(256), 0, stream,
                     x, Wq, Wk, Wv, Wo, xbf, wqbf, wkbf, wvbf, wobf);
  hipLaunchKernelGGL(qkv_gemm, dim3(768), dim3(256), 0, stream,
                     xbf, wqbf, wkbf, wvbf, bq, bk, bv, qws, kws, vws);
  hipLaunchKernelGGL(attn_kernel, dim3(8, 32, 2), dim3(256), 0, stream,
                     qws, kws, vws, aws);
  hipLaunchKernelGGL(out_gemm, dim3(512), dim3(256), 0, stream,
                     aws, wobf, bo, out);
}

// Round 14
// 199.932 us; speedup vs baseline: 1.1676x; 1.1676x over previous
//
#include <hip/hip_runtime.h>
#include <stdint.h>

// GQA fused forward: B=2, S=1024, HIDDEN=2048, H=32, G=8, D=64, causal.
// I/O float32; internal bf16 MFMA. Mask input ignored (causal from indices).
//
// Pipeline (round 14: restore best-known r12 config after r13 regression):
//   0) cvt:       f32 -> bf16 copies of x, Wq, Wk, Wv, Wo (exact-fit 1D grid)
//   1) qkv_gemm:  128x64 tiles, 768 blocks (3/CU), dbuf staging, fused
//                 bias+scatter (direct stores). XCD-rect swizzle 8m x 12ty.
//   2) attn:      S^T-form flash attention, paired q-tiles, Q direct from
//                 global, LDS-staged dbuf K/V + setprio, diagonal-only
//                 masking, exact skip-rescale, v_perm packing.
//   3) out_gemm:  dbuf core, 512 blocks (2/CU), fused bias -> f32 out
//                 (direct stores). XCD-rect swizzle 8m x 8ty.
//
// NOTE (round-1): never fuse cross-block reductions via atomics+fences
// (device __threadfence -> buffer_wbl2/inv, 38us -> 150us).
// NOTE (round-4): do not split attn into more blocks/CU (staging contention).
// NOTE (round-6): GEMMs are staging/issue-latency-bound, not HBM-BW-bound.
// NOTE (round-7): weights must reach GEMMs as bf16 via global_load_lds.
// NOTE (round-8): GEMM dbuf neutral (TLP already hides staging latency).
// NOTE (round-9/10): attn VALU diet + KV-sharing neutral.
// NOTE (round-11): LDS-bounce epilogues regressed (bank conflicts + barriers).
// NOTE (round-13): K/V-direct-from-global attn REGRESSED 48->68us: the LDS
// staging is the latency-hiding engine (one global_load_lds stream prefetches
// a tile ahead for all 4 waves); per-wave global loads expose ~200-400cy L2
// latency x24 loads/step that 2 waves/SIMD cannot cover. The ~1700cy/step is
// the dependent chain at this occupancy, not a removable barrier convoy.
// Do not remove attn LDS staging.

typedef __bf16 bf16_8 __attribute__((ext_vector_type(8)));
typedef float f32x4 __attribute__((ext_vector_type(4)));

__device__ __forceinline__ unsigned short f2bf(float f) {
  union { float f; unsigned int i; } c; c.f = f;
  unsigned int u = c.i;
  return (unsigned short)((u + 0x7fffu + ((u >> 16) & 1u)) >> 16);
}

__device__ __forceinline__ void gl2lds16(const void* g, void* l) {
  __builtin_amdgcn_global_load_lds(
      (const __attribute__((address_space(1))) void*)g,
      (__attribute__((address_space(3))) void*)l, 16, 0, 0);
}

// Stage ROWS x 64 bf16 tile (leading dim ldg) into LDS; per-row XOR swizzle of
// 8-elem groups: LDS[r][lg] = G[r][lg ^ (r&7)]. 256 threads.
template <int ROWS>
__device__ __forceinline__ void stage_tile(const unsigned short* g, int ldg,
                                           unsigned short* lds, int tid) {
#pragma unroll
  for (int i = 0; i < ROWS * 8 / 256; ++i) {
    int c = tid + i * 256;
    int r = c >> 3;
    int grp = (c & 7) ^ (r & 7);
    gl2lds16(g + (size_t)r * ldg + grp * 8, lds + c * 8);
  }
}

// Core 128x64 GEMM tile: Y = X[128,K] @ W[64,K]^T (leading dim ld).
// 4 waves, each owns a 32x64 output stripe: acc[2][4] of 16x16 frags.
// Double-buffered: one barrier per K-step; stage(k+1) issued before MFMA(k).
__device__ __forceinline__ void gemm_core_n64(const unsigned short* Xt,
                                              const unsigned short* Wt,
                                              int kiter, int ld, int tid,
                                              unsigned short* sA,
                                              unsigned short* sB,
                                              f32x4 acc[2][4]) {
  const int wave = tid >> 6, lane = tid & 63;
  const int wm = wave << 5;
  const int lrow = lane & 15, quad = lane >> 4;
  stage_tile<128>(Xt, ld, sA, tid);
  stage_tile<64>(Wt, ld, sB, tid);
  int cur = 0;
  for (int k0 = 0; k0 < kiter; k0 += 64) {
    __syncthreads();  // staging(buf[cur]) drained; buf[cur^1] reads done
    if (k0 + 64 < kiter) {
      stage_tile<128>(Xt + k0 + 64, ld, sA + ((cur ^ 1) << 13), tid);
      stage_tile<64>(Wt + k0 + 64, ld, sB + ((cur ^ 1) << 12), tid);
    }
    const unsigned short* A = sA + (cur << 13);
    const unsigned short* Bt = sB + (cur << 12);
#pragma unroll
    for (int ks = 0; ks < 2; ++ks) {
      bf16_8 af[2], bw[4];
#pragma unroll
      for (int i = 0; i < 2; ++i) {
        int ra = wm + i * 16 + lrow;
        af[i] = *(const bf16_8*)(A + ra * 64 + (((ks << 2) + quad) ^ (ra & 7)) * 8);
      }
#pragma unroll
      for (int j = 0; j < 4; ++j) {
        int rb = j * 16 + lrow;
        bw[j] = *(const bf16_8*)(Bt + rb * 64 + (((ks << 2) + quad) ^ (rb & 7)) * 8);
      }
#pragma unroll
      for (int i = 0; i < 2; ++i)
#pragma unroll
        for (int j = 0; j < 4; ++j)
          acc[i][j] = __builtin_amdgcn_mfma_f32_16x16x32_bf16(af[i], bw[j],
                                                              acc[i][j], 0, 0, 0);
    }
    cur ^= 1;
  }
}

// ---------------- kernel 0: f32 -> bf16 conversion (exact-fit 1D grid) ------
// 14336 blocks: x 4096 | Wq 4096 | Wk 1024 | Wv 1024 | Wo 4096.
__global__ void __launch_bounds__(256)
cvt_kernel(const float* __restrict__ s0, const float* __restrict__ s1,
           const float* __restrict__ s2, const float* __restrict__ s3,
           const float* __restrict__ s4,
           unsigned short* __restrict__ d0, unsigned short* __restrict__ d1,
           unsigned short* __restrict__ d2, unsigned short* __restrict__ d3,
           unsigned short* __restrict__ d4) {
  const int bid = blockIdx.x;
  const float* src; unsigned short* dst; int off;
  if (bid < 4096)       { src = s0; dst = d0; off = bid; }
  else if (bid < 8192)  { src = s1; dst = d1; off = bid - 4096; }
  else if (bid < 9216)  { src = s2; dst = d2; off = bid - 8192; }
  else if (bid < 10240) { src = s3; dst = d3; off = bid - 9216; }
  else                  { src = s4; dst = d4; off = bid - 10240; }
  int idx = (off * 256 + threadIdx.x) * 4;
  float4 v = *(const float4*)(src + idx);
  ushort4 o;
  o.x = f2bf(v.x); o.y = f2bf(v.y); o.z = f2bf(v.z); o.w = f2bf(v.w);
  *(ushort4*)(dst + idx) = o;
}

// ---------------- kernel 1: QKV projection, fused bias+scatter -------------
// 1D grid (768). XCD-rect swizzle: xcd=bid&7 owns an 8m x 12ty rectangle.
// ty 0..31 -> Q head ty; 32..39 -> K group; 40..47 -> V group (n = ty*64).
// Direct epilogue stores (r11 lesson: LDS bounce adds conflicts + barriers).
__global__ void __launch_bounds__(256)
qkv_gemm(const unsigned short* __restrict__ X,
         const unsigned short* __restrict__ Wq,
         const unsigned short* __restrict__ Wk,
         const unsigned short* __restrict__ Wv,
         const float* __restrict__ bq, const float* __restrict__ bk,
         const float* __restrict__ bv,
         unsigned short* __restrict__ qws, unsigned short* __restrict__ kws,
         unsigned short* __restrict__ vws) {
  __shared__ unsigned short sA[2 * 128 * 64], sB[2 * 64 * 64];
  const int tid = threadIdx.x;
  const int bid = blockIdx.x;
  const int xcd = bid & 7, idx = bid >> 3;        // 96 blocks per XCD
  const int mt  = ((xcd & 1) << 3) + idx / 12;    // [0,16)
  const int ty  = (xcd >> 1) * 12 + idx % 12;     // [0,48)
  const int tileM = mt * 128;
  const unsigned short* W;
  const float* bias;
  if (ty < 32)      { W = Wq + (size_t)ty * 64 * 2048;        bias = bq + ty * 64; }
  else if (ty < 40) { W = Wk + (size_t)(ty - 32) * 64 * 2048; bias = bk + (ty - 32) * 64; }
  else              { W = Wv + (size_t)(ty - 40) * 64 * 2048; bias = bv + (ty - 40) * 64; }

  f32x4 acc[2][4] = {};
  gemm_core_n64(X + (size_t)tileM * 2048, W, 2048, 2048, tid, sA, sB, acc);

  const int wave = tid >> 6, lane = tid & 63;
  const int wm = wave << 5;
  const int lrow = lane & 15, quad = lane >> 4;

#pragma unroll
  for (int j = 0; j < 4; ++j) {
    const int dloc = j * 16 + lrow;          // 0..63: dim within this 64-slice
    const float bj = bias[dloc];
#pragma unroll
    for (int i = 0; i < 2; ++i) {
      const int mbase = tileM + wm + i * 16 + quad * 4;
      const int b = mbase >> 10;
      const int s = mbase & 1023;            // s, s+1, s+2, s+3 for r=0..3
      if (ty < 32) {
        unsigned short* p = qws + ((((size_t)b * 32 + ty) << 10) + s) * 64 + dloc;
#pragma unroll
        for (int r = 0; r < 4; ++r) p[r * 64] = f2bf(acc[i][j][r] + bj);
      } else if (ty < 40) {
        unsigned short* p = kws + ((((size_t)b * 8 + (ty - 32)) << 10) + s) * 64 + dloc;
#pragma unroll
        for (int r = 0; r < 4; ++r) p[r * 64] = f2bf(acc[i][j][r] + bj);
      } else {
        // vws[b, g, d, s] (transposed): r=0..3 are consecutive s -> pack 8B
        unsigned short* p = vws + ((((size_t)b * 8 + (ty - 40)) * 64 + dloc) << 10) + s;
        uint2 pk;
        pk.x = f2bf(acc[i][j][0] + bj) | ((unsigned int)f2bf(acc[i][j][1] + bj) << 16);
        pk.y = f2bf(acc[i][j][2] + bj) | ((unsigned int)f2bf(acc[i][j][3] + bj) << 16);
        *(uint2*)p = pk;
      }
    }
  }
}

// ---------------- attn tile step (templated on causal masking) --------------
// MASKED=true only for the diagonal tile (kc==qt) -- the only tile where the
// causal mask can bite. Skip-rescale: when no lane's tile-max exceeds m_i,
// alpha==1.0 exactly -> rescale is a bit-identical no-op. v_perm_b32 packing.
template <bool MASKED>
__device__ __forceinline__ void attn_step(
    const unsigned short* __restrict__ sKc,
    const unsigned short* __restrict__ sVc,
    unsigned short* __restrict__ sPt,
    const bf16_8 (&qf)[2], int lrow, int quad, int qloc,
    int kvb, int q_g, float C, float& m_i, float& l_i, f32x4 (&o)[4]) {
  f32x4 sc[4] = {};
  __builtin_amdgcn_s_setprio(1);
#pragma unroll
  for (int kh = 0; kh < 2; ++kh)
#pragma unroll
    for (int mt = 0; mt < 4; ++mt) {
      int kv = mt * 16 + lrow;
      bf16_8 kf = *(const bf16_8*)(sKc + kv * 64 + (((kh << 2) + quad) ^ (kv & 7)) * 8);
      sc[mt] = __builtin_amdgcn_mfma_f32_16x16x32_bf16(kf, qf[kh], sc[mt], 0, 0, 0);
    }
  __builtin_amdgcn_s_setprio(0);

  float mx = -INFINITY;
#pragma unroll
  for (int mt = 0; mt < 4; ++mt)
#pragma unroll
    for (int r = 0; r < 4; ++r) {
      float v = sc[mt][r];
      if constexpr (MASKED) {
        if (kvb + mt * 16 + r > q_g) v = -INFINITY;
        sc[mt][r] = v;
      }
      mx = fmaxf(mx, v);
    }
  mx = fmaxf(mx, __shfl_xor(mx, 16));
  mx = fmaxf(mx, __shfl_xor(mx, 32));

  const bool grow = __any(mx > m_i);
  float alpha = 1.f;
  if (grow) {
    float mnew = fmaxf(m_i, mx);
    alpha = exp2f((m_i - mnew) * C);
    m_i = mnew;
  }
  float sum = 0.f;
#pragma unroll
  for (int mt = 0; mt < 4; ++mt)
#pragma unroll
    for (int r = 0; r < 4; ++r) {
      float p = exp2f((sc[mt][r] - m_i) * C);
      sc[mt][r] = p;
      sum += p;
    }
  sum += __shfl_xor(sum, 16);
  sum += __shfl_xor(sum, 32);
  if (grow) {
    l_i = l_i * alpha + sum;
#pragma unroll
    for (int mt = 0; mt < 4; ++mt)
#pragma unroll
      for (int r = 0; r < 4; ++r) o[mt][r] *= alpha;
  } else {
    l_i += sum;
  }

#pragma unroll
  for (int mt = 0; mt < 4; ++mt) {
    unsigned int a0 = __float_as_uint(sc[mt][0]), a1 = __float_as_uint(sc[mt][1]);
    unsigned int a2 = __float_as_uint(sc[mt][2]), a3 = __float_as_uint(sc[mt][3]);
    uint2 pk;
    pk.x = __builtin_amdgcn_perm(a1, a0, 0x07060302u);  // (a0>>16)|(a1&hi16)
    pk.y = __builtin_amdgcn_perm(a3, a2, 0x07060302u);
    int grp = (mt * 4 + quad) ^ lrow;
    *(uint2*)(sPt + qloc * 64 + grp * 4) = pk;
  }

  __builtin_amdgcn_s_setprio(1);
#pragma unroll
  for (int kh = 0; kh < 2; ++kh) {
    int gbase = kh * 8 + quad * 2;
    uint2 b0 = *(const uint2*)(sPt + qloc * 64 + ((gbase) ^ lrow) * 4);
    uint2 b1 = *(const uint2*)(sPt + qloc * 64 + ((gbase + 1) ^ lrow) * 4);
    union { uint4 u; bf16_8 v; } bb;
    bb.u = make_uint4(b0.x, b0.y, b1.x, b1.y);
#pragma unroll
    for (int mt = 0; mt < 4; ++mt) {
      int d = mt * 16 + lrow;
      bf16_8 vf = *(const bf16_8*)(sVc + d * 64 + (((kh << 2) + quad) ^ (d & 7)) * 8);
      o[mt] = __builtin_amdgcn_mfma_f32_16x16x32_bf16(vf, bb.v, o[mt], 0, 0, 0);
    }
  }
  __builtin_amdgcn_s_setprio(0);
}

// ---------------- kernel 2: causal flash attention (S^T form) ----------------
// grid (8, 32, 2): (pair, head, batch). Block handles q-tiles {x, 15-x}:
// uniform 17 kc-iters per block, XCD-balanced by construction. Q fragments
// loaded direct from global (no sQ; LDS 40KB). Double-buffered K/V staging:
// 1 barrier/iter, next tile staged before compute. Diagonal handled last.
__global__ void __launch_bounds__(256)
attn_kernel(const unsigned short* __restrict__ Qw, const unsigned short* __restrict__ Kw,
            const unsigned short* __restrict__ Vt, unsigned short* __restrict__ Ow) {
  __shared__ unsigned short sK[2][64 * 64], sVt[2][64 * 64], sPt[64 * 64];
  const int tid = threadIdx.x;
  const int pair = blockIdx.x, h = blockIdx.y, b = blockIdx.z;
  const int g = h >> 2;
  const unsigned short* Kb = Kw + (((size_t)b * 8 + g) << 16);  // [s][d]
  const unsigned short* Vb = Vt + (((size_t)b * 8 + g) << 16);  // [d][s], ld=1024
  const int wave = tid >> 6, lane = tid & 63;
  const int lrow = lane & 15, quad = lane >> 4;
  const int qloc = wave * 16 + lrow;
  const float C = 0.18033688f;  // 0.125 * log2(e)

#pragma unroll 1
  for (int t = 0; t < 2; ++t) {
    const int qt = t ? (15 - pair) : pair;
    __syncthreads();  // protect sK/sVt/sPt reuse across t iterations

    // Q fragments straight from global: Q[b,h, qt*64+qloc, (kh*4+quad)*8 ..+8]
    const unsigned short* Qrow =
        Qw + ((((size_t)b * 32 + h) << 10) + qt * 64 + qloc) * 64;
    bf16_8 qf[2];
#pragma unroll
    for (int kh = 0; kh < 2; ++kh)
      qf[kh] = *(const bf16_8*)(Qrow + ((kh << 2) + quad) * 8);

    stage_tile<64>(Kb, 64, sK[0], tid);
    stage_tile<64>(Vb, 1024, sVt[0], tid);
    __syncthreads();

    float m_i = -INFINITY, l_i = 0.f;
    f32x4 o[4] = {};
    const int q_g = qt * 64 + qloc;
    int cur = 0;

    // non-diagonal tiles: no causal masking possible
#pragma unroll 1
    for (int kc = 0; kc < qt; ++kc) {
      if (kc) __syncthreads();  // staging of buf[cur] done; buf[cur^1] free
      // issue next-tile staging BEFORE compute: latency hides under MFMA
      stage_tile<64>(Kb + (size_t)(kc + 1) * 64 * 64, 64, sK[cur ^ 1], tid);
      stage_tile<64>(Vb + (kc + 1) * 64, 1024, sVt[cur ^ 1], tid);
      attn_step<false>(sK[cur], sVt[cur], sPt, qf, lrow, quad, qloc,
                       kc * 64 + quad * 4, q_g, C, m_i, l_i, o);
      cur ^= 1;
    }
    // diagonal tile (kc == qt): the only tile the causal mask touches
    if (qt) __syncthreads();
    attn_step<true>(sK[cur], sVt[cur], sPt, qf, lrow, quad, qloc,
                    qt * 64 + quad * 4, q_g, C, m_i, l_i, o);

    float inv = 1.f / l_i;
#pragma unroll
    for (int mt = 0; mt < 4; ++mt) {
      uint2 pk;
      pk.x = f2bf(o[mt][0] * inv) | ((unsigned int)f2bf(o[mt][1] * inv) << 16);
      pk.y = f2bf(o[mt][2] * inv) | ((unsigned int)f2bf(o[mt][3] * inv) << 16);
      int grp = (mt * 4 + quad) ^ lrow;
      *(uint2*)(sPt + qloc * 64 + grp * 4) = pk;
    }
    __syncthreads();
    {
      int row = tid >> 2, seg = tid & 3;
      uint2 w0 = *(const uint2*)(sPt + row * 64 + ((seg * 4 + 0) ^ (row & 15)) * 4);
      uint2 w1 = *(const uint2*)(sPt + row * 64 + ((seg * 4 + 1) ^ (row & 15)) * 4);
      uint2 w2 = *(const uint2*)(sPt + row * 64 + ((seg * 4 + 2) ^ (row & 15)) * 4);
      uint2 w3 = *(const uint2*)(sPt + row * 64 + ((seg * 4 + 3) ^ (row & 15)) * 4);
      size_t base = ((((size_t)b << 10) + qt * 64 + row) << 11) + h * 64 + seg * 16;
      *(uint4*)(Ow + base) = make_uint4(w0.x, w0.y, w1.x, w1.y);
      *(uint4*)(Ow + base + 8) = make_uint4(w2.x, w2.y, w3.x, w3.y);
    }
  }
}

// ---------------- kernel 3: output projection, fused bias -> f32 out --------
// 1D grid (512). XCD-rect swizzle: xcd=bid&7 owns an 8m x 8ty rectangle.
// Direct epilogue stores (r11 lesson).
__global__ void __launch_bounds__(256)
out_gemm(const unsigned short* __restrict__ X, const unsigned short* __restrict__ Wo,
         const float* __restrict__ bo, float* __restrict__ out) {
  __shared__ unsigned short sA[2 * 128 * 64], sB[2 * 64 * 64];
  const int tid = threadIdx.x;
  const int bid = blockIdx.x;
  const int xcd = bid & 7, idx = bid >> 3;        // 64 blocks per XCD
  const int mt  = ((xcd & 1) << 3) + (idx >> 3);  // [0,16)
  const int ty  = ((xcd >> 1) << 3) + (idx & 7);  // [0,32)
  const int tileM = mt * 128, tileN = ty * 64;
  f32x4 acc[2][4] = {};
  gemm_core_n64(X + (size_t)tileM * 2048, Wo + (size_t)tileN * 2048, 2048, 2048,
                tid, sA, sB, acc);

  const int wave = tid >> 6, lane = tid & 63;
  const int wm = wave << 5;
  const int lrow = lane & 15, quad = lane >> 4;
#pragma unroll
  for (int j = 0; j < 4; ++j) {
    const int n = tileN + j * 16 + lrow;
    const float bj = bo[n];
#pragma unroll
    for (int i = 0; i < 2; ++i) {
      const int mbase = tileM + wm + i * 16 + quad * 4;
#pragma unroll
      for (int r = 0; r < 4; ++r)
        out[(size_t)(mbase + r) * 2048 + n] = acc[i][j][r] + bj;
    }
  }
}

extern "C" void kernel_launch(void* const* d_in, const int* in_sizes, int n_in,
                              void* d_out, int out_size, void* d_ws, size_t ws_size,
                              hipStream_t stream) {
  const float* x  = (const float*)d_in[0];
  const float* Wq = (const float*)d_in[2];
  const float* bq = (const float*)d_in[3];
  const float* Wk = (const float*)d_in[4];
  const float* bk = (const float*)d_in[5];
  const float* Wv = (const float*)d_in[6];
  const float* bv = (const float*)d_in[7];
  const float* Wo = (const float*)d_in[8];
  const float* bo = (const float*)d_in[9];

  unsigned short* xbf  = (unsigned short*)d_ws;                  // 4,194,304 el
  unsigned short* wqbf = xbf  + (size_t)4194304;
  unsigned short* wkbf = wqbf + (size_t)4194304;
  unsigned short* wvbf = wkbf + (size_t)1048576;
  unsigned short* wobf = wvbf + (size_t)1048576;
  unsigned short* qws  = wobf + (size_t)4194304;                 // [2,32,1024,64]
  unsigned short* kws  = qws  + (size_t)2 * 32 * 1024 * 64;      // [2,8,1024,64]
  unsigned short* vws  = kws  + (size_t)2 * 8 * 1024 * 64;       // [2,8,64,1024]
  unsigned short* aws  = vws  + (size_t)2 * 8 * 1024 * 64;       // [2,1024,2048]
  float* out = (float*)d_out;

  hipLaunchKernelGGL(cvt_kernel, dim3(14336), dim3(256), 0, stream,
                     x, Wq, Wk, Wv, Wo, xbf, wqbf, wkbf, wvbf, wobf);
  hipLaunchKernelGGL(qkv_gemm, dim3(768), dim3(256), 0, stream,
                     xbf, wqbf, wkbf, wvbf, bq, bk, bv, qws, kws, vws);
  hipLaunchKernelGGL(attn_kernel, dim3(8, 32, 2), dim3(256), 0, stream,
                     qws, kws, vws, aws);
  hipLaunchKernelGGL(out_gemm, dim3(512), dim3(256), 0, stream,
                     aws, wobf, bo, out);
}